// Round 7
// baseline (54.875 us; speedup 1.0000x reference)
//
#include <hip/hip_runtime.h>
#include <math.h>

// ---------------------------------------------------------------------------
// DRR forward projection, LDS-brick v2.
//
// Model (r1/r5 data): dur ~= vmem lane-addresses / (1 addr/cyc/CU). Gather
// structure is floored at 4 addr/sample (~41us). This version stages interior
// bricks in LDS (~1.7 addr/sample) and falls back to the proven self-gating
// gather algebra for boundary chunks.
//
// march (drr6): 1-wave blocks (64 thr). Block = (16x16 px tile) x (1 of 5
// step segments). Chunk = 3 steps. Brick AABB analytic from 4 corner rays
// (coords bilinear in (px,py,alpha) -> corner-extremal). Interior chunk:
// reg-stage brick rows (dwordx4 -> 2x ds_write_b64, row stride 18 words to
// break bank resonance), then pure ungated trilerp from LDS (interior =>
// all 8 corners in-bounds => reference contributes full trilerp).
// Boundary chunk: drr4 gather path (weights self-gate OOB corners exactly).
// Partials per segment -> reduce kernel applies seglen.
// ---------------------------------------------------------------------------

typedef float f2 __attribute__((ext_vector_type(2), aligned(4)));
typedef float f4 __attribute__((ext_vector_type(4), aligned(4)));

#define TSZ 16
#define SEG 5
#define CST 3
#define BSY 20          // brick row cap (x and y)
#define SZW 18          // words per row (16 staged + 2 pad)
#define BRICKW (BSY*BSY*SZW)   // 7200 words = 28.8 KB

__device__ __forceinline__ void inv4x4(const float* m, float* inv) {
    inv[0]  =  m[5]*m[10]*m[15] - m[5]*m[11]*m[14] - m[9]*m[6]*m[15] + m[9]*m[7]*m[14] + m[13]*m[6]*m[11] - m[13]*m[7]*m[10];
    inv[4]  = -m[4]*m[10]*m[15] + m[4]*m[11]*m[14] + m[8]*m[6]*m[15] - m[8]*m[7]*m[14] - m[12]*m[6]*m[11] + m[12]*m[7]*m[10];
    inv[8]  =  m[4]*m[9]*m[15]  - m[4]*m[11]*m[13] - m[8]*m[5]*m[15] + m[8]*m[7]*m[13] + m[12]*m[5]*m[11] - m[12]*m[7]*m[9];
    inv[12] = -m[4]*m[9]*m[14]  + m[4]*m[10]*m[13] + m[8]*m[5]*m[14] - m[8]*m[6]*m[13] - m[12]*m[5]*m[10] + m[12]*m[6]*m[9];
    inv[1]  = -m[1]*m[10]*m[15] + m[1]*m[11]*m[14] + m[9]*m[2]*m[15] - m[9]*m[3]*m[14] - m[13]*m[2]*m[11] + m[13]*m[3]*m[10];
    inv[5]  =  m[0]*m[10]*m[15] - m[0]*m[11]*m[14] - m[8]*m[2]*m[15] + m[8]*m[3]*m[14] + m[12]*m[2]*m[11] - m[12]*m[3]*m[10];
    inv[9]  = -m[0]*m[9]*m[15]  + m[0]*m[11]*m[13] + m[8]*m[1]*m[15] - m[8]*m[3]*m[13] - m[12]*m[1]*m[11] + m[12]*m[3]*m[9];
    inv[13] =  m[0]*m[9]*m[14]  - m[0]*m[10]*m[13] - m[8]*m[1]*m[14] + m[8]*m[2]*m[13] + m[12]*m[1]*m[10] - m[12]*m[2]*m[9];
    inv[2]  =  m[1]*m[6]*m[15]  - m[1]*m[7]*m[14]  - m[5]*m[2]*m[15] + m[5]*m[3]*m[14] + m[13]*m[2]*m[7]  - m[13]*m[3]*m[6];
    inv[6]  = -m[0]*m[6]*m[15]  + m[0]*m[7]*m[14]  + m[4]*m[2]*m[15] - m[4]*m[3]*m[14] - m[12]*m[2]*m[7]  + m[12]*m[3]*m[6];
    inv[10] =  m[0]*m[5]*m[15]  - m[0]*m[7]*m[13]  - m[4]*m[1]*m[15] + m[4]*m[3]*m[13] + m[12]*m[1]*m[7]  - m[12]*m[3]*m[5];
    inv[14] = -m[0]*m[5]*m[14]  + m[0]*m[6]*m[13]  + m[4]*m[1]*m[14] - m[4]*m[2]*m[13] - m[12]*m[1]*m[6]  + m[12]*m[2]*m[5];
    inv[3]  = -m[1]*m[6]*m[11]  + m[1]*m[7]*m[10]  + m[5]*m[2]*m[11] - m[5]*m[3]*m[10] - m[9]*m[2]*m[7]   + m[9]*m[3]*m[6];
    inv[7]  =  m[0]*m[6]*m[11]  - m[0]*m[7]*m[10]  - m[4]*m[2]*m[11] + m[4]*m[3]*m[10] + m[8]*m[2]*m[7]   - m[8]*m[3]*m[6];
    inv[11] = -m[0]*m[5]*m[11]  + m[0]*m[7]*m[9]   + m[4]*m[1]*m[11] - m[4]*m[3]*m[9]  - m[8]*m[1]*m[7]   + m[8]*m[3]*m[5];
    inv[15] =  m[0]*m[5]*m[10]  - m[0]*m[6]*m[9]   - m[4]*m[1]*m[10] + m[4]*m[2]*m[9]  + m[8]*m[1]*m[6]   - m[8]*m[2]*m[5];
    float det = m[0]*inv[0] + m[1]*inv[4] + m[2]*inv[8] + m[3]*inv[12];
    float rd = 1.0f/det;
    for (int k = 0; k < 16; ++k) inv[k] *= rd;
}

// Per-batch params: P[b*24 + 0..8]=A1, [9..17]=A2, [18..20]=p0
__global__ void setup_k(const float* __restrict__ rt_inv, const float* __restrict__ k_inv,
                        const float* __restrict__ sdd,    const float* __restrict__ iso,
                        const float* __restrict__ affine, const float* __restrict__ rot,
                        const float* __restrict__ xyz,    float* __restrict__ P, int B)
{
    int b = blockIdx.x * blockDim.x + threadIdx.x;
    if (b >= B) return;

    const float* Mi = rt_inv + (size_t)b * 16;
    float rt[16];
    inv4x4(Mi, rt);

    float c[3];
    for (int r = 0; r < 3; ++r)
        c[r] = rt[r*4+0]*iso[0] + rt[r*4+1]*iso[1] + rt[r*4+2]*iso[2] + rt[r*4+3];

    float rx = rot[b*3+0], ry = rot[b*3+1], rz = rot[b*3+2];
    float th = sqrtf(rx*rx + ry*ry + rz*rz);
    float Rr[9];
    if (th < 1e-8f) {
        Rr[0]=1.f; Rr[1]=0.f; Rr[2]=0.f;
        Rr[3]=0.f; Rr[4]=1.f; Rr[5]=0.f;
        Rr[6]=0.f; Rr[7]=0.f; Rr[8]=1.f;
    } else {
        float kx = rx/th, ky = ry/th, kz = rz/th;
        float s = sinf(th), ct = cosf(th), v = 1.f - ct;
        Rr[0] = ct + v*kx*kx;     Rr[1] = v*kx*ky - s*kz;  Rr[2] = v*kx*kz + s*ky;
        Rr[3] = v*ky*kx + s*kz;   Rr[4] = ct + v*ky*ky;    Rr[5] = v*ky*kz - s*kx;
        Rr[6] = v*kz*kx - s*ky;   Rr[7] = v*kz*ky + s*kx;  Rr[8] = ct + v*kz*kz;
    }

    float tp[3];
    for (int r = 0; r < 3; ++r)
        tp[r] = c[r] + xyz[b*3+r] - (Rr[r*3+0]*c[0] + Rr[r*3+1]*c[1] + Rr[r*3+2]*c[2]);

    float G[9], t[3];
    for (int r = 0; r < 3; ++r) {
        for (int cc = 0; cc < 3; ++cc)
            G[r*3+cc] = Mi[r*4+0]*Rr[0*3+cc] + Mi[r*4+1]*Rr[1*3+cc] + Mi[r*4+2]*Rr[2*3+cc];
        t[r] = Mi[r*4+0]*tp[0] + Mi[r*4+1]*tp[1] + Mi[r*4+2]*tp[2] + Mi[r*4+3];
    }

    float Ai[16];
    inv4x4(affine, Ai);

    float p0[3];
    for (int r = 0; r < 3; ++r)
        p0[r] = Ai[r*4+0]*t[0] + Ai[r*4+1]*t[1] + Ai[r*4+2]*t[2] + Ai[r*4+3];

    float MG[9];
    for (int r = 0; r < 3; ++r)
        for (int cc = 0; cc < 3; ++cc)
            MG[r*3+cc] = Ai[r*4+0]*G[0*3+cc] + Ai[r*4+1]*G[1*3+cc] + Ai[r*4+2]*G[2*3+cc];

    const float* Ki = k_inv + (size_t)b * 9;
    float sd = sdd[b];
    float* Pb = P + (size_t)b * 24;
    for (int r = 0; r < 3; ++r)
        for (int cc = 0; cc < 3; ++cc) {
            Pb[r*3+cc]     = (MG[r*3+0]*Ki[0*3+cc] + MG[r*3+1]*Ki[1*3+cc] + MG[r*3+2]*Ki[2*3+cc]) * sd;
            Pb[9 + r*3+cc] = (G[r*3+0]*Ki[0*3+cc]  + G[r*3+1]*Ki[1*3+cc]  + G[r*3+2]*Ki[2*3+cc])  * sd;
        }
    Pb[18] = p0[0]; Pb[19] = p0[1]; Pb[20] = p0[2];
}

// self-gating trilinear gather from global (exactly reference's inb semantics)
__device__ __forceinline__ float sample_g(const float* __restrict__ vol, int D,
                                          float x, float y, float z)
{
    float fx = floorf(x), fy = floorf(y), fz = floorf(z);
    int ix = (int)fx, iy = (int)fy, iz = (int)fz;
    float tx = x - fx, ty = y - fy, tz = z - fz;
    const int D1 = D - 1;
    int x0c = min(max(ix, 0), D1), x1c = min(max(ix + 1, 0), D1);
    int y0c = min(max(iy, 0), D1), y1c = min(max(iy + 1, 0), D1);
    int z0c = min(max(iz, 0), D - 2);
    int a0r = x0c * D, a1r = x1c * D;
    f2 q00 = *(const f2*)(vol + (unsigned)((a0r + y0c) * D + z0c));
    f2 q01 = *(const f2*)(vol + (unsigned)((a0r + y1c) * D + z0c));
    f2 q10 = *(const f2*)(vol + (unsigned)((a1r + y0c) * D + z0c));
    f2 q11 = *(const f2*)(vol + (unsigned)((a1r + y1c) * D + z0c));
    bool e0 = (iz == z0c), em = (iz == z0c - 1), ep = (iz == z0c + 1);
    float v0, v1, c00, c01, c10, c11;
    v0 = e0 ? q00.x : (ep ? q00.y : 0.f);
    v1 = e0 ? q00.y : (em ? q00.x : 0.f);
    c00 = fmaf(tz, v1 - v0, v0);
    v0 = e0 ? q01.x : (ep ? q01.y : 0.f);
    v1 = e0 ? q01.y : (em ? q01.x : 0.f);
    c01 = fmaf(tz, v1 - v0, v0);
    v0 = e0 ? q10.x : (ep ? q10.y : 0.f);
    v1 = e0 ? q10.y : (em ? q10.x : 0.f);
    c10 = fmaf(tz, v1 - v0, v0);
    v0 = e0 ? q11.x : (ep ? q11.y : 0.f);
    v1 = e0 ? q11.y : (em ? q11.x : 0.f);
    c11 = fmaf(tz, v1 - v0, v0);
    float wy0 = ((unsigned)iy       < (unsigned)D) ? 1.f - ty : 0.f;
    float wy1 = ((unsigned)(iy + 1) < (unsigned)D) ? ty       : 0.f;
    float wx0 = ((unsigned)ix       < (unsigned)D) ? 1.f - tx : 0.f;
    float wx1 = ((unsigned)(ix + 1) < (unsigned)D) ? tx       : 0.f;
    float s0 = fmaf(wy0, c00, wy1 * c01);
    float s1 = fmaf(wy0, c10, wy1 * c11);
    return fmaf(wx0, s0, wx1 * s1);
}

// 1-wave march kernel: block = (16x16 px tile) x (step segment)
__global__ void __launch_bounds__(64) drr6(
        const float* __restrict__ vol, const float* __restrict__ P,
        float* __restrict__ partial,
        const int* __restrict__ Hp, const int* __restrict__ Wp, const int* __restrict__ Sp,
        int B, int D)
{
    __shared__ float brick[BRICKW];

    const int H = *Hp, W = *Wp, S = *Sp;
    const int npix = H * W;
    const int nTj = (W + TSZ - 1) / TSZ, nTi = (H + TSZ - 1) / TSZ;
    const int ntile = B * nTi * nTj;
    const long long nblk = (long long)ntile * SEG;
    const int lane = threadIdx.x;
    const float Sf = (float)S, invS = 1.0f / Sf;
    const float LOW = -1.001f, HIW = (float)D + 0.001f;

    for (long long vb = blockIdx.x; vb < nblk; vb += gridDim.x) {
        // m204 bijective XCD swizzle (same-tile segments stay on one XCD)
        long long q8 = nblk >> 3; int r8 = (int)(nblk & 7);
        int xcd = (int)(vb & 7);
        long long lin = ((xcd < r8) ? (long long)xcd * (q8 + 1)
                                    : (long long)r8 * (q8 + 1) + (long long)(xcd - r8) * q8)
                        + (vb >> 3);
        int tile = (int)(lin / SEG);
        int seg  = (int)(lin - (long long)tile * SEG);
        int b = 0, tl = tile;
        if (B > 1) { b = tile / (nTi * nTj); tl = tile - b * (nTi * nTj); }
        int ti = tl / nTj, tj = tl - ti * nTj;

        const float* Pb = P + 24 * b;
        const float p0x = Pb[18], p0y = Pb[19], p0z = Pb[20];

        // tile corner rays (clamped to valid pixels)
        float cddx[4], cddy[4], cddz[4];
        {
            float pxs[2] = { tj * TSZ + 0.5f, min(tj * TSZ + TSZ - 1, W - 1) + 0.5f };
            float pys[2] = { ti * TSZ + 0.5f, min(ti * TSZ + TSZ - 1, H - 1) + 0.5f };
            #pragma unroll
            for (int a = 0; a < 2; ++a)
                #pragma unroll
                for (int bb = 0; bb < 2; ++bb) {
                    int k = a * 2 + bb;
                    cddx[k] = fmaf(Pb[0], pxs[a], fmaf(Pb[1], pys[bb], Pb[2]));
                    cddy[k] = fmaf(Pb[3], pxs[a], fmaf(Pb[4], pys[bb], Pb[5]));
                    cddz[k] = fmaf(Pb[6], pxs[a], fmaf(Pb[7], pys[bb], Pb[8]));
                }
        }

        // block step window from z-slab over corners (conservative)
        float ain = 1.f, aout = 0.f;
        #pragma unroll
        for (int k = 0; k < 4; ++k) {
            float d = cddz[k], t0, t1;
            if (fabsf(d) > 1e-12f) { float ri = 1.f / d; t0 = (LOW - p0z) * ri; t1 = (HIW - p0z) * ri; }
            else { t0 = 0.f; t1 = 1.f; }
            ain = fminf(ain, fminf(t0, t1));
            aout = fmaxf(aout, fmaxf(t0, t1));
        }
        ain = fmaxf(ain, 0.f); aout = fminf(aout, 1.f);
        int sbeg = (int)ceilf(ain * Sf - 0.5f) - 1; if (sbeg < 0) sbeg = 0;
        int send = (int)floorf(aout * Sf - 0.5f) + 1; if (send > S - 1) send = S - 1;
        int nchunk = (send >= sbeg) ? (send - sbeg) / CST + 1 : 0;

        // my 4 pixels
        float ddx[4], ddy[4], ddz[4], acc[4];
        int prr[4], pcc[4]; bool vld[4];
        #pragma unroll
        for (int pp = 0; pp < 4; ++pp) {
            int idx = lane + (pp << 6);
            int u = idx >> 4, v = idx & 15;
            int r = ti * TSZ + u, c = tj * TSZ + v;
            vld[pp] = (r < H) && (c < W);
            int r2 = min(r, H - 1), c2 = min(c, W - 1);
            prr[pp] = r2; pcc[pp] = c2;
            float px = c2 + 0.5f, py = r2 + 0.5f;
            ddx[pp] = fmaf(Pb[0], px, fmaf(Pb[1], py, Pb[2]));
            ddy[pp] = fmaf(Pb[3], px, fmaf(Pb[4], py, Pb[5]));
            ddz[pp] = fmaf(Pb[6], px, fmaf(Pb[7], py, Pb[8]));
            acc[pp] = 0.f;
        }

        for (int ch = seg; ch < nchunk; ch += SEG) {
            int s0 = sbeg + ch * CST;
            int sl = min(s0 + CST - 1, send);
            float alA = (s0 + 0.5f) * invS, alB = (sl + 0.5f) * invS;

            // chunk AABB from 8 corner evals (bilinear -> corner-extremal)
            float mnx = 1e30f, mny = 1e30f, mnz = 1e30f;
            float mxx = -1e30f, mxy = -1e30f, mxz = -1e30f;
            #pragma unroll
            for (int k = 0; k < 4; ++k) {
                float xA = fmaf(alA, cddx[k], p0x), xB = fmaf(alB, cddx[k], p0x);
                float yA = fmaf(alA, cddy[k], p0y), yB = fmaf(alB, cddy[k], p0y);
                float zA = fmaf(alA, cddz[k], p0z), zB = fmaf(alB, cddz[k], p0z);
                mnx = fminf(mnx, fminf(xA, xB)); mxx = fmaxf(mxx, fmaxf(xA, xB));
                mny = fminf(mny, fminf(yA, yB)); mxy = fmaxf(mxy, fmaxf(yA, yB));
                mnz = fminf(mnz, fminf(zA, zB)); mxz = fmaxf(mxz, fmaxf(zA, zB));
            }
            int bx = (int)floorf(mnx), by = (int)floorf(mny);
            int zb4 = ((int)floorf(mnz)) & ~3;
            int sx = (int)floorf(mxx) - bx + 2;
            int sy = (int)floorf(mxy) - by + 2;
            int zw = (int)floorf(mxz) + 2 - zb4;
            float Dm1 = (float)(D - 1);
            bool inter = (D >= 20) && ((D & 3) == 0) &&
                         (mnx >= 0.f) && (mxx < Dm1) &&
                         (mny >= 0.f) && (mxy < Dm1) &&
                         (mnz >= 0.f) && (mxz < Dm1) &&
                         (sx <= BSY) && (sy <= BSY) && (zw <= 16);

            if (inter) {
                // stage: rows [bx..bx+sx-1] x [by..by+sy-1], 16 z-words each
                int sy4 = sy << 2;
                int tot = sx * sy4;
                float isy4 = 1.f / (float)sy4;
                for (int k = lane; k < tot; k += 64) {
                    int i = (int)((k + 0.5f) * isy4);
                    int rem = k - i * sy4;
                    int j = rem >> 2, g = rem & 3;
                    const float* src = vol + ((size_t)(bx + i) * D + (by + j)) * D + zb4 + (g << 2);
                    f4 qv = *(const f4*)src;
                    int dst = (i * BSY + j) * SZW + (g << 2);
                    *(f2*)(brick + dst)     = (f2){ qv.x, qv.y };
                    *(f2*)(brick + dst + 2) = (f2){ qv.z, qv.w };
                }
                __syncthreads();
                #pragma unroll
                for (int pp = 0; pp < 4; ++pp) {
                    if (!vld[pp]) continue;
                    #pragma unroll
                    for (int ss = 0; ss < CST; ++ss) {
                        int s = s0 + ss;
                        if (s > sl) break;
                        float al = (s + 0.5f) * invS;
                        float x = fmaf(al, ddx[pp], p0x);
                        float y = fmaf(al, ddy[pp], p0y);
                        float z = fmaf(al, ddz[pp], p0z);
                        float fx = floorf(x), fy = floorf(y), fz = floorf(z);
                        int ix = (int)fx, iy = (int)fy, iz = (int)fz;
                        float tx = x - fx, ty = y - fy, tz = z - fz;
                        int base = ((ix - bx) * BSY + (iy - by)) * SZW + (iz - zb4);
                        float v000 = brick[base],                 v001 = brick[base + 1];
                        float v010 = brick[base + SZW],           v011 = brick[base + SZW + 1];
                        float v100 = brick[base + BSY * SZW],     v101 = brick[base + BSY * SZW + 1];
                        float v110 = brick[base + (BSY + 1) * SZW], v111 = brick[base + (BSY + 1) * SZW + 1];
                        float c00 = fmaf(tz, v001 - v000, v000);
                        float c01 = fmaf(tz, v011 - v010, v010);
                        float c10 = fmaf(tz, v101 - v100, v100);
                        float c11 = fmaf(tz, v111 - v110, v110);
                        float c0  = fmaf(ty, c01 - c00, c00);
                        float c1  = fmaf(ty, c11 - c10, c10);
                        acc[pp] += fmaf(tx, c1 - c0, c0);
                    }
                }
                __syncthreads();
            } else {
                // boundary chunk: proven self-gating gather path
                #pragma unroll
                for (int pp = 0; pp < 4; ++pp) {
                    if (!vld[pp]) continue;
                    #pragma unroll
                    for (int ss = 0; ss < CST; ++ss) {
                        int s = s0 + ss;
                        if (s > sl) break;
                        float al = (s + 0.5f) * invS;
                        float x = fmaf(al, ddx[pp], p0x);
                        float y = fmaf(al, ddy[pp], p0y);
                        float z = fmaf(al, ddz[pp], p0z);
                        acc[pp] += sample_g(vol, D, x, y, z);
                    }
                }
            }
        }

        #pragma unroll
        for (int pp = 0; pp < 4; ++pp)
            if (vld[pp])
                partial[((size_t)seg * B + b) * npix + (size_t)prr[pp] * W + pcc[pp]] = acc[pp];
    }
}

// sum segment partials, apply seglen
__global__ void reduce_k(const float* __restrict__ P, const float* __restrict__ partial,
                         float* __restrict__ out,
                         const int* __restrict__ Hp, const int* __restrict__ Wp,
                         const int* __restrict__ Sp, int B)
{
    int H = *Hp, W = *Wp, S = *Sp;
    int npix = H * W;
    int gid = blockIdx.x * 256 + threadIdx.x;
    if (gid >= B * npix) return;
    int b = gid / npix, pix = gid - b * npix;
    int i = pix / W, j = pix - i * W;
    const float* Pb = P + 24 * b;
    float px = j + 0.5f, py = i + 0.5f;
    float rx = fmaf(Pb[9],  px, fmaf(Pb[10], py, Pb[11]));
    float ry = fmaf(Pb[12], px, fmaf(Pb[13], py, Pb[14]));
    float rz = fmaf(Pb[15], px, fmaf(Pb[16], py, Pb[17]));
    float seglen = sqrtf(rx*rx + ry*ry + rz*rz) / (float)S;
    float s = 0.f;
    #pragma unroll
    for (int g = 0; g < SEG; ++g)
        s += partial[((size_t)g * B + b) * npix + pix];
    out[gid] = s * seglen;
}

// fallback (ws too small for partials): drr4-equivalent per-pixel gather
__global__ void __launch_bounds__(256, 4) drr_fb(
        const float* __restrict__ vol, const float* __restrict__ P,
        float* __restrict__ out,
        const int* __restrict__ Hp, const int* __restrict__ Wp, const int* __restrict__ Sp,
        int B, int D)
{
    const int H = *Hp, W = *Wp, S = *Sp;
    const int npix = H * W;
    long long tot = (long long)B * npix * 16;   // 16 lanes per pixel
    const float Sf = (float)S, invS = 1.0f / Sf;
    const float lo = -1.001f, hi = (float)D + 0.001f;
    for (long long g = (long long)blockIdx.x * blockDim.x + threadIdx.x; g < tot;
         g += (long long)gridDim.x * blockDim.x) {
        int t = (int)(g & 15);
        long long pg = g >> 4;
        int b = (int)(pg / npix);
        int pix = (int)(pg - (long long)b * npix);
        int i = pix / W, j = pix - i * W;
        const float* Pb = P + 24 * b;
        float px = j + 0.5f, py = i + 0.5f;
        float ddx = fmaf(Pb[0], px, fmaf(Pb[1], py, Pb[2]));
        float ddy = fmaf(Pb[3], px, fmaf(Pb[4], py, Pb[5]));
        float ddz = fmaf(Pb[6], px, fmaf(Pb[7], py, Pb[8]));
        float rxx = fmaf(Pb[9], px, fmaf(Pb[10], py, Pb[11]));
        float ryy = fmaf(Pb[12], px, fmaf(Pb[13], py, Pb[14]));
        float rzz = fmaf(Pb[15], px, fmaf(Pb[16], py, Pb[17]));
        float p0x = Pb[18], p0y = Pb[19], p0z = Pb[20];
        float seglen = sqrtf(rxx*rxx + ryy*ryy + rzz*rzz) * invS;
        float a0 = 0.f, a1 = 1.f;
        float ppv[3] = {p0x, p0y, p0z};
        float ddv[3] = {ddx, ddy, ddz};
        #pragma unroll
        for (int ax = 0; ax < 3; ++ax) {
            if (fabsf(ddv[ax]) > 1e-12f) {
                float r = 1.0f / ddv[ax];
                float t0 = (lo - ppv[ax]) * r, t1 = (hi - ppv[ax]) * r;
                a0 = fmaxf(a0, fminf(t0, t1));
                a1 = fminf(a1, fmaxf(t0, t1));
            } else if (ppv[ax] < lo || ppv[ax] > hi) a1 = -1.0f;
        }
        int slo = (int)ceilf(a0 * Sf - 0.5f) - 1; if (slo < 0) slo = 0;
        int shi = (int)floorf(a1 * Sf - 0.5f) + 1; if (shi > S - 1) shi = S - 1;
        float sum = 0.f;
        for (int s = slo + t; s <= shi; s += 16) {
            float al = (s + 0.5f) * invS;
            sum += sample_g(vol, D, fmaf(al, ddx, p0x), fmaf(al, ddy, p0y), fmaf(al, ddz, p0z));
        }
        sum += __shfl_xor(sum, 8, 16);
        sum += __shfl_xor(sum, 4, 16);
        sum += __shfl_xor(sum, 2, 16);
        sum += __shfl_xor(sum, 1, 16);
        if (t == 0) out[pg] = sum * seglen;
    }
}

extern "C" void kernel_launch(void* const* d_in, const int* in_sizes, int n_in,
                              void* d_out, int out_size, void* d_ws, size_t ws_size,
                              hipStream_t stream)
{
    const float* volume = (const float*)d_in[0];
    const float* rt_inv = (const float*)d_in[1];
    const float* k_inv  = (const float*)d_in[2];
    const float* sdd    = (const float*)d_in[3];
    const float* iso    = (const float*)d_in[4];
    const float* affine = (const float*)d_in[5];
    const float* rot    = (const float*)d_in[6];
    const float* xyz    = (const float*)d_in[7];
    const int*   Hp     = (const int*)d_in[8];
    const int*   Wp     = (const int*)d_in[9];
    const int*   Sp     = (const int*)d_in[10];

    int B = in_sizes[1] / 16;                         // rt_inv is (B,4,4)
    int D = (int)lroundf(cbrtf((float)in_sizes[0]));  // volume is (D,D,D)
    long long hw = (long long)out_size / B;

    float* P = (float*)d_ws;
    setup_k<<<(B + 63) / 64, 64, 0, stream>>>(rt_inv, k_inv, sdd, iso, affine, rot, xyz, P, B);

    size_t offP = ((size_t)24 * B * 4 + 255) & ~(size_t)255;
    size_t needPart = (size_t)SEG * out_size * 4;

    if (ws_size >= offP + needPart) {
        float* partial = (float*)((char*)d_ws + offP);
        drr6<<<2048, 64, 0, stream>>>(volume, P, partial, Hp, Wp, Sp, B, D);
        int rg = (out_size + 255) / 256;
        reduce_k<<<rg, 256, 0, stream>>>(P, partial, (float*)d_out, Hp, Wp, Sp, B);
    } else {
        long long threads = (long long)out_size * 16;
        long long grid = (threads + 255) / 256;
        if (grid > (1 << 20)) grid = (1 << 20);
        drr_fb<<<(int)grid, 256, 0, stream>>>(volume, P, (float*)d_out, Hp, Wp, Sp, B, D);
    }
    (void)n_in; (void)hw;
}

// Round 8
// 40.951 us; speedup vs baseline: 1.3400x; 1.3400x over previous
//
#include <hip/hip_runtime.h>
#include <math.h>

// ---------------------------------------------------------------------------
// DRR forward projection: per-pixel ray march through D^3 volume, trilinear.
//
// Model (r1/r5/r6 data): dur ~= gather lane-addresses / (~1 addr/cyc/CU).
// drr4 (4 addr/sample) sits at that floor. This version shares loads across
// a 2x2 PIXEL QUAD per lane: when the quad's 8-corner footprint fits a
// 3x3x2 interior box (x/y floor-spread<=1, z bit-equal, interior), nine 8B
// z-pair loads serve all 4 samples (2.25 addr/sample). Shared z-lerp ->
// 9 scalars; per-pixel exact select-weighted 3x3 bilinear. Slots failing the
// conditions use the proven self-gating gather (exact reference semantics).
//
// Wave = 4 quads x 16 step-lanes. Slab clip, supertile XCD swizzle kept.
// LDS staging abandoned (r4/r7: serialization eats the address saving).
// ---------------------------------------------------------------------------

typedef float f2 __attribute__((ext_vector_type(2), aligned(4)));

__device__ __forceinline__ void inv4x4(const float* m, float* inv) {
    inv[0]  =  m[5]*m[10]*m[15] - m[5]*m[11]*m[14] - m[9]*m[6]*m[15] + m[9]*m[7]*m[14] + m[13]*m[6]*m[11] - m[13]*m[7]*m[10];
    inv[4]  = -m[4]*m[10]*m[15] + m[4]*m[11]*m[14] + m[8]*m[6]*m[15] - m[8]*m[7]*m[14] - m[12]*m[6]*m[11] + m[12]*m[7]*m[10];
    inv[8]  =  m[4]*m[9]*m[15]  - m[4]*m[11]*m[13] - m[8]*m[5]*m[15] + m[8]*m[7]*m[13] + m[12]*m[5]*m[11] - m[12]*m[7]*m[9];
    inv[12] = -m[4]*m[9]*m[14]  + m[4]*m[10]*m[13] + m[8]*m[5]*m[14] - m[8]*m[6]*m[13] - m[12]*m[5]*m[10] + m[12]*m[6]*m[9];
    inv[1]  = -m[1]*m[10]*m[15] + m[1]*m[11]*m[14] + m[9]*m[2]*m[15] - m[9]*m[3]*m[14] - m[13]*m[2]*m[11] + m[13]*m[3]*m[10];
    inv[5]  =  m[0]*m[10]*m[15] - m[0]*m[11]*m[14] - m[8]*m[2]*m[15] + m[8]*m[3]*m[14] + m[12]*m[2]*m[11] - m[12]*m[3]*m[10];
    inv[9]  = -m[0]*m[9]*m[15]  + m[0]*m[11]*m[13] + m[8]*m[1]*m[15] - m[8]*m[3]*m[13] - m[12]*m[1]*m[11] + m[12]*m[3]*m[9];
    inv[13] =  m[0]*m[9]*m[14]  - m[0]*m[10]*m[13] - m[8]*m[1]*m[14] + m[8]*m[2]*m[13] + m[12]*m[1]*m[10] - m[12]*m[2]*m[9];
    inv[2]  =  m[1]*m[6]*m[15]  - m[1]*m[7]*m[14]  - m[5]*m[2]*m[15] + m[5]*m[3]*m[14] + m[13]*m[2]*m[7]  - m[13]*m[3]*m[6];
    inv[6]  = -m[0]*m[6]*m[15]  + m[0]*m[7]*m[14]  + m[4]*m[2]*m[15] - m[4]*m[3]*m[14] - m[12]*m[2]*m[7]  + m[12]*m[3]*m[6];
    inv[10] =  m[0]*m[5]*m[15]  - m[0]*m[7]*m[13]  - m[4]*m[1]*m[15] + m[4]*m[3]*m[13] + m[12]*m[1]*m[7]  - m[12]*m[3]*m[5];
    inv[14] = -m[0]*m[5]*m[14]  + m[0]*m[6]*m[13]  + m[4]*m[1]*m[14] - m[4]*m[2]*m[13] - m[12]*m[1]*m[6]  + m[12]*m[2]*m[5];
    inv[3]  = -m[1]*m[6]*m[11]  + m[1]*m[7]*m[10]  + m[5]*m[2]*m[11] - m[5]*m[3]*m[10] - m[9]*m[2]*m[7]   + m[9]*m[3]*m[6];
    inv[7]  =  m[0]*m[6]*m[11]  - m[0]*m[7]*m[10]  - m[4]*m[2]*m[11] + m[4]*m[3]*m[10] + m[8]*m[2]*m[7]   - m[8]*m[3]*m[6];
    inv[11] = -m[0]*m[5]*m[11]  + m[0]*m[7]*m[9]   + m[4]*m[1]*m[11] - m[4]*m[3]*m[9]  - m[8]*m[1]*m[7]   + m[8]*m[3]*m[5];
    inv[15] =  m[0]*m[5]*m[10]  - m[0]*m[6]*m[9]   - m[4]*m[1]*m[10] + m[4]*m[2]*m[9]  + m[8]*m[1]*m[6]   - m[8]*m[2]*m[5];
    float det = m[0]*inv[0] + m[1]*inv[4] + m[2]*inv[8] + m[3]*inv[12];
    float rd = 1.0f/det;
    for (int k = 0; k < 16; ++k) inv[k] *= rd;
}

// Per-batch params: P[b*24 + 0..8]=A1, [9..17]=A2, [18..20]=p0
__global__ void setup_k(const float* __restrict__ rt_inv, const float* __restrict__ k_inv,
                        const float* __restrict__ sdd,    const float* __restrict__ iso,
                        const float* __restrict__ affine, const float* __restrict__ rot,
                        const float* __restrict__ xyz,    float* __restrict__ P, int B)
{
    int b = blockIdx.x * blockDim.x + threadIdx.x;
    if (b >= B) return;

    const float* Mi = rt_inv + (size_t)b * 16;
    float rt[16];
    inv4x4(Mi, rt);

    float c[3];
    for (int r = 0; r < 3; ++r)
        c[r] = rt[r*4+0]*iso[0] + rt[r*4+1]*iso[1] + rt[r*4+2]*iso[2] + rt[r*4+3];

    float rx = rot[b*3+0], ry = rot[b*3+1], rz = rot[b*3+2];
    float th = sqrtf(rx*rx + ry*ry + rz*rz);
    float Rr[9];
    if (th < 1e-8f) {
        Rr[0]=1.f; Rr[1]=0.f; Rr[2]=0.f;
        Rr[3]=0.f; Rr[4]=1.f; Rr[5]=0.f;
        Rr[6]=0.f; Rr[7]=0.f; Rr[8]=1.f;
    } else {
        float kx = rx/th, ky = ry/th, kz = rz/th;
        float s = sinf(th), ct = cosf(th), v = 1.f - ct;
        Rr[0] = ct + v*kx*kx;     Rr[1] = v*kx*ky - s*kz;  Rr[2] = v*kx*kz + s*ky;
        Rr[3] = v*ky*kx + s*kz;   Rr[4] = ct + v*ky*ky;    Rr[5] = v*ky*kz - s*kx;
        Rr[6] = v*kz*kx - s*ky;   Rr[7] = v*kz*ky + s*kx;  Rr[8] = ct + v*kz*kz;
    }

    float tp[3];
    for (int r = 0; r < 3; ++r)
        tp[r] = c[r] + xyz[b*3+r] - (Rr[r*3+0]*c[0] + Rr[r*3+1]*c[1] + Rr[r*3+2]*c[2]);

    float G[9], t[3];
    for (int r = 0; r < 3; ++r) {
        for (int cc = 0; cc < 3; ++cc)
            G[r*3+cc] = Mi[r*4+0]*Rr[0*3+cc] + Mi[r*4+1]*Rr[1*3+cc] + Mi[r*4+2]*Rr[2*3+cc];
        t[r] = Mi[r*4+0]*tp[0] + Mi[r*4+1]*tp[1] + Mi[r*4+2]*tp[2] + Mi[r*4+3];
    }

    float Ai[16];
    inv4x4(affine, Ai);

    float p0[3];
    for (int r = 0; r < 3; ++r)
        p0[r] = Ai[r*4+0]*t[0] + Ai[r*4+1]*t[1] + Ai[r*4+2]*t[2] + Ai[r*4+3];

    float MG[9];
    for (int r = 0; r < 3; ++r)
        for (int cc = 0; cc < 3; ++cc)
            MG[r*3+cc] = Ai[r*4+0]*G[0*3+cc] + Ai[r*4+1]*G[1*3+cc] + Ai[r*4+2]*G[2*3+cc];

    const float* Ki = k_inv + (size_t)b * 9;
    float sd = sdd[b];
    float* Pb = P + (size_t)b * 24;
    for (int r = 0; r < 3; ++r)
        for (int cc = 0; cc < 3; ++cc) {
            Pb[r*3+cc]     = (MG[r*3+0]*Ki[0*3+cc] + MG[r*3+1]*Ki[1*3+cc] + MG[r*3+2]*Ki[2*3+cc]) * sd;
            Pb[9 + r*3+cc] = (G[r*3+0]*Ki[0*3+cc]  + G[r*3+1]*Ki[1*3+cc]  + G[r*3+2]*Ki[2*3+cc])  * sd;
        }
    Pb[18] = p0[0]; Pb[19] = p0[1]; Pb[20] = p0[2];
}

// self-gating trilinear gather (exactly reference's inb semantics)
__device__ __forceinline__ float sample_g(const float* __restrict__ vol, int D,
                                          float x, float y, float z)
{
    float fx = floorf(x), fy = floorf(y), fz = floorf(z);
    int ix = (int)fx, iy = (int)fy, iz = (int)fz;
    float tx = x - fx, ty = y - fy, tz = z - fz;
    const int D1 = D - 1;
    int x0c = min(max(ix, 0), D1), x1c = min(max(ix + 1, 0), D1);
    int y0c = min(max(iy, 0), D1), y1c = min(max(iy + 1, 0), D1);
    int z0c = min(max(iz, 0), D - 2);
    int a0r = x0c * D, a1r = x1c * D;
    f2 q00 = *(const f2*)(vol + (unsigned)((a0r + y0c) * D + z0c));
    f2 q01 = *(const f2*)(vol + (unsigned)((a0r + y1c) * D + z0c));
    f2 q10 = *(const f2*)(vol + (unsigned)((a1r + y0c) * D + z0c));
    f2 q11 = *(const f2*)(vol + (unsigned)((a1r + y1c) * D + z0c));
    bool e0 = (iz == z0c), em = (iz == z0c - 1), ep = (iz == z0c + 1);
    float v0, v1, c00, c01, c10, c11;
    v0 = e0 ? q00.x : (ep ? q00.y : 0.f);
    v1 = e0 ? q00.y : (em ? q00.x : 0.f);
    c00 = fmaf(tz, v1 - v0, v0);
    v0 = e0 ? q01.x : (ep ? q01.y : 0.f);
    v1 = e0 ? q01.y : (em ? q01.x : 0.f);
    c01 = fmaf(tz, v1 - v0, v0);
    v0 = e0 ? q10.x : (ep ? q10.y : 0.f);
    v1 = e0 ? q10.y : (em ? q10.x : 0.f);
    c10 = fmaf(tz, v1 - v0, v0);
    v0 = e0 ? q11.x : (ep ? q11.y : 0.f);
    v1 = e0 ? q11.y : (em ? q11.x : 0.f);
    c11 = fmaf(tz, v1 - v0, v0);
    float wy0 = ((unsigned)iy       < (unsigned)D) ? 1.f - ty : 0.f;
    float wy1 = ((unsigned)(iy + 1) < (unsigned)D) ? ty       : 0.f;
    float wx0 = ((unsigned)ix       < (unsigned)D) ? 1.f - tx : 0.f;
    float wx1 = ((unsigned)(ix + 1) < (unsigned)D) ? tx       : 0.f;
    float s0 = fmaf(wy0, c00, wy1 * c01);
    float s1 = fmaf(wy0, c10, wy1 * c11);
    return fmaf(wx0, s0, wx1 * s1);
}

// 1 lane = one 2x2 pixel quad at one step; 16 step-lanes per quad;
// wave = 4 quads; block (256 thr) = 16 quads = 8x8 px; 64 blocks = 64x64
// supertile, chunked per XCD.
__global__ void __launch_bounds__(256, 4) drr7(
        const float* __restrict__ vol, const float* __restrict__ P,
        float* __restrict__ out,
        const int* __restrict__ Hp, const int* __restrict__ Wp, const int* __restrict__ Sp,
        int B, int D)
{
    const int H = *Hp, W = *Wp, S = *Sp;
    const int npix = H * W;
    const int nSj = (W + 63) >> 6, nSi = (H + 63) >> 6;
    const int nS = nSi * nSj;
    const int nStot = B * nS;
    const long long nVB = (long long)nStot << 6;   // 64 blocks per supertile

    const int tid  = threadIdx.x;
    const int wave = tid >> 6, lane = tid & 63;
    const int q    = lane >> 4, t = lane & 15;
    const int DD   = D * D;
    const float Sf = (float)S, invS = 1.0f / Sf;

    for (long long vb = blockIdx.x; vb < nVB; vb += gridDim.x) {
        int st, within;
        if ((nStot & 7) == 0) {
            int xcd = (int)(vb & 7);
            long long slot = vb >> 3;
            st = xcd * (nStot >> 3) + (int)(slot >> 6);
            within = (int)(slot & 63);
        } else {
            st = (int)(vb >> 6);
            within = (int)(vb & 63);
        }
        int b = 0, stl = st;
        if (B > 1) { b = st / nS; stl = st - b * nS; }
        int si = stl / nSj, sj = stl - si * nSj;

        int idx = (wave << 2) + q, qr = idx >> 2, qc = idx & 3;
        int r0 = (si << 6) + ((within >> 3) << 3) + (qr << 1);
        int c0 = (sj << 6) + ((within & 7) << 3) + (qc << 1);

        const float* Pb = P + 24 * __builtin_amdgcn_readfirstlane(b);
        const float p0x = Pb[18], p0y = Pb[19], p0z = Pb[20];

        float ddx[4], ddy[4], ddz[4], segl[4];
        int pr[4], pc[4]; bool vld[4];
        int sloQ = 0x7fffffff, shiQ = -0x7fffffff;
        const float lo = -1.001f, hi = (float)D + 0.001f;

        #pragma unroll
        for (int p2 = 0; p2 < 4; ++p2) {
            int rr = r0 + (p2 >> 1), cc = c0 + (p2 & 1);
            vld[p2] = (rr < H) && (cc < W);
            rr = min(rr, H - 1); cc = min(cc, W - 1);
            pr[p2] = rr; pc[p2] = cc;
            float px = cc + 0.5f, py = rr + 0.5f;
            float dx_ = fmaf(Pb[0], px, fmaf(Pb[1], py, Pb[2]));
            float dy_ = fmaf(Pb[3], px, fmaf(Pb[4], py, Pb[5]));
            float dz_ = fmaf(Pb[6], px, fmaf(Pb[7], py, Pb[8]));
            ddx[p2] = dx_; ddy[p2] = dy_; ddz[p2] = dz_;
            float rx = fmaf(Pb[9],  px, fmaf(Pb[10], py, Pb[11]));
            float ry = fmaf(Pb[12], px, fmaf(Pb[13], py, Pb[14]));
            float rz = fmaf(Pb[15], px, fmaf(Pb[16], py, Pb[17]));
            segl[p2] = sqrtf(rx*rx + ry*ry + rz*rz) * invS;
            float a0 = 0.f, a1 = 1.f;
            float pp3[3] = {p0x, p0y, p0z};
            float dd3[3] = {dx_, dy_, dz_};
            #pragma unroll
            for (int ax = 0; ax < 3; ++ax) {
                if (fabsf(dd3[ax]) > 1e-12f) {
                    float ri = 1.0f / dd3[ax];
                    float t0 = (lo - pp3[ax]) * ri;
                    float t1 = (hi - pp3[ax]) * ri;
                    a0 = fmaxf(a0, fminf(t0, t1));
                    a1 = fminf(a1, fmaxf(t0, t1));
                } else if (pp3[ax] < lo || pp3[ax] > hi) {
                    a1 = -1.0f;
                }
            }
            int slo = (int)ceilf(a0 * Sf - 0.5f) - 1; if (slo < 0) slo = 0;
            int shi = (int)floorf(a1 * Sf - 0.5f) + 1; if (shi > S - 1) shi = S - 1;
            sloQ = min(sloQ, slo); shiQ = max(shiQ, shi);
        }

        float acc[4] = {0.f, 0.f, 0.f, 0.f};

        if (shiQ >= sloQ) {
            #pragma unroll
            for (int it = 0; it < 6; ++it) {
                int s = sloQ + t + (it << 4);
                if (s <= shiQ) {
                    float al = (s + 0.5f) * invS;
                    float X4[4], Y4[4], Z4[4], FX[4], FY[4];
                    int IX[4], IY[4];
                    #pragma unroll
                    for (int p2 = 0; p2 < 4; ++p2) {
                        X4[p2] = fmaf(al, ddx[p2], p0x);
                        Y4[p2] = fmaf(al, ddy[p2], p0y);
                        Z4[p2] = fmaf(al, ddz[p2], p0z);
                        FX[p2] = floorf(X4[p2]); IX[p2] = (int)FX[p2];
                        FY[p2] = floorf(Y4[p2]); IY[p2] = (int)FY[p2];
                    }
                    int Xm = min(min(IX[0], IX[1]), min(IX[2], IX[3]));
                    int XM = max(max(IX[0], IX[1]), max(IX[2], IX[3]));
                    int Ym = min(min(IY[0], IY[1]), min(IY[2], IY[3]));
                    int YM = max(max(IY[0], IY[1]), max(IY[2], IY[3]));
                    bool zeq = (Z4[0] == Z4[1]) && (Z4[1] == Z4[2]) && (Z4[2] == Z4[3]);
                    float fz = floorf(Z4[0]); int Z = (int)fz; float tzc = Z4[0] - fz;
                    bool fast = zeq && (XM - Xm <= 1) && (YM - Ym <= 1) &&
                                (Xm >= 0) && (Xm <= D - 3) &&
                                (Ym >= 0) && (Ym <= D - 3) &&
                                (Z  >= 0) && (Z  <= D - 2);
                    if (fast) {
                        unsigned base = (unsigned)((Xm * D + Ym) * D + Z);
                        f2 q00 = *(const f2*)(vol + base);
                        f2 q01 = *(const f2*)(vol + base + D);
                        f2 q02 = *(const f2*)(vol + base + 2*D);
                        f2 q10 = *(const f2*)(vol + base + DD);
                        f2 q11 = *(const f2*)(vol + base + DD + D);
                        f2 q12 = *(const f2*)(vol + base + DD + 2*D);
                        f2 q20 = *(const f2*)(vol + base + 2*DD);
                        f2 q21 = *(const f2*)(vol + base + 2*DD + D);
                        f2 q22 = *(const f2*)(vol + base + 2*DD + 2*D);
                        float m00 = fmaf(tzc, q00.y - q00.x, q00.x);
                        float m01 = fmaf(tzc, q01.y - q01.x, q01.x);
                        float m02 = fmaf(tzc, q02.y - q02.x, q02.x);
                        float m10 = fmaf(tzc, q10.y - q10.x, q10.x);
                        float m11 = fmaf(tzc, q11.y - q11.x, q11.x);
                        float m12 = fmaf(tzc, q12.y - q12.x, q12.x);
                        float m20 = fmaf(tzc, q20.y - q20.x, q20.x);
                        float m21 = fmaf(tzc, q21.y - q21.x, q21.x);
                        float m22 = fmaf(tzc, q22.y - q22.x, q22.x);
                        #pragma unroll
                        for (int p2 = 0; p2 < 4; ++p2) {
                            float tx = X4[p2] - FX[p2];
                            float ty = Y4[p2] - FY[p2];
                            bool sx = (IX[p2] != Xm), sy = (IY[p2] != Ym);
                            float ux = 1.f - tx, uy = 1.f - ty;
                            float wx0 = sx ? 0.f : ux, wx1 = sx ? ux : tx, wx2 = sx ? tx : 0.f;
                            float wy0 = sy ? 0.f : uy, wy1 = sy ? uy : ty, wy2 = sy ? ty : 0.f;
                            float h0 = m00 * wy0; h0 = fmaf(m01, wy1, h0); h0 = fmaf(m02, wy2, h0);
                            float h1 = m10 * wy0; h1 = fmaf(m11, wy1, h1); h1 = fmaf(m12, wy2, h1);
                            float h2 = m20 * wy0; h2 = fmaf(m21, wy1, h2); h2 = fmaf(m22, wy2, h2);
                            float v = wx0 * h0; v = fmaf(wx1, h1, v); v = fmaf(wx2, h2, v);
                            acc[p2] += v;
                        }
                    } else {
                        #pragma unroll
                        for (int p2 = 0; p2 < 4; ++p2)
                            acc[p2] += sample_g(vol, D, X4[p2], Y4[p2], Z4[p2]);
                    }
                }
            }
            // generic tail (quad range > 96; not taken for this geometry)
            for (int s = sloQ + 96 + t; s <= shiQ; s += 16) {
                float al = (s + 0.5f) * invS;
                #pragma unroll
                for (int p2 = 0; p2 < 4; ++p2)
                    acc[p2] += sample_g(vol, D,
                                        fmaf(al, ddx[p2], p0x),
                                        fmaf(al, ddy[p2], p0y),
                                        fmaf(al, ddz[p2], p0z));
            }
        }

        #pragma unroll
        for (int p2 = 0; p2 < 4; ++p2) {
            float v = acc[p2];
            v += __shfl_xor(v, 8, 16);
            v += __shfl_xor(v, 4, 16);
            v += __shfl_xor(v, 2, 16);
            v += __shfl_xor(v, 1, 16);
            acc[p2] = v;
        }

        if (t == 0) {
            #pragma unroll
            for (int p2 = 0; p2 < 4; ++p2)
                if (vld[p2])
                    out[(size_t)b * npix + (size_t)pr[p2] * W + pc[p2]] = acc[p2] * segl[p2];
        }
    }
}

extern "C" void kernel_launch(void* const* d_in, const int* in_sizes, int n_in,
                              void* d_out, int out_size, void* d_ws, size_t ws_size,
                              hipStream_t stream)
{
    const float* volume = (const float*)d_in[0];
    const float* rt_inv = (const float*)d_in[1];
    const float* k_inv  = (const float*)d_in[2];
    const float* sdd    = (const float*)d_in[3];
    const float* iso    = (const float*)d_in[4];
    const float* affine = (const float*)d_in[5];
    const float* rot    = (const float*)d_in[6];
    const float* xyz    = (const float*)d_in[7];
    const int*   Hp     = (const int*)d_in[8];
    const int*   Wp     = (const int*)d_in[9];
    const int*   Sp     = (const int*)d_in[10];

    int B = in_sizes[1] / 16;                         // rt_inv is (B,4,4)
    int D = (int)lroundf(cbrtf((float)in_sizes[0]));  // volume is (D,D,D)

    float* P = (float*)d_ws;
    setup_k<<<(B + 63) / 64, 64, 0, stream>>>(rt_inv, k_inv, sdd, iso, affine, rot, xyz, P, B);

    // 64 blocks per 64x64 supertile; device loop grid-strides any remainder
    long long hw = (long long)out_size / B;
    long long vbl = (long long)B * ((hw + 4095) >> 12) * 64;
    if (vbl < 1) vbl = 1;
    if (vbl > (1 << 22)) vbl = (1 << 22);
    drr7<<<(int)vbl, 256, 0, stream>>>(volume, P, (float*)d_out, Hp, Wp, Sp, B, D);
    (void)n_in; (void)ws_size;
}

// Round 9
// 38.310 us; speedup vs baseline: 1.4324x; 1.0689x over previous
//
#include <hip/hip_runtime.h>
#include <math.h>

// ---------------------------------------------------------------------------
// DRR forward projection: per-pixel ray march through D^3 volume, trilinear.
//
// setup_k: folds all small linear algebra into 21 per-batch floats:
//   vox(s) = p0 + alpha_s*(A1@pixh), ray = A2@pixh, seglen = |ray|/S.
//
// drr8 == round-5's drr4 (best known: wall 38.8us, profiled 47.4, VGPR 64)
// with ONE change: __launch_bounds__(256,4) -> (256,6). Round-5 counters
// showed occupancy 46% sitting exactly at the self-imposed 4-block/CU cap;
// grid offers 16 blocks/CU. This A/B-tests latency-gap vs TA-throughput-
// floor: model floor = 25.2M lane-addresses / (256CU x 2.4GHz) = 41us.
//   - 1 wave = 4 pixels (1x4 strip), 16 lanes/pixel striding over steps
//   - analytic slab clip to the (-1,D) support box (outside = exact 0)
//   - phase-split 6x4 pair-gathers (no fence; r6 showed fence => scratch)
//   - z-corner pair as one 8B load (clamped base + branchless select)
//   - x/y out-of-bounds folded into lerp weights (matches reference inb)
//   - XCD-aware 64x64-pixel supertile swizzle (halved FETCH_SIZE in r3)
// ---------------------------------------------------------------------------

typedef float f2 __attribute__((ext_vector_type(2), aligned(4)));

__device__ __forceinline__ void inv4x4(const float* m, float* inv) {
    inv[0]  =  m[5]*m[10]*m[15] - m[5]*m[11]*m[14] - m[9]*m[6]*m[15] + m[9]*m[7]*m[14] + m[13]*m[6]*m[11] - m[13]*m[7]*m[10];
    inv[4]  = -m[4]*m[10]*m[15] + m[4]*m[11]*m[14] + m[8]*m[6]*m[15] - m[8]*m[7]*m[14] - m[12]*m[6]*m[11] + m[12]*m[7]*m[10];
    inv[8]  =  m[4]*m[9]*m[15]  - m[4]*m[11]*m[13] - m[8]*m[5]*m[15] + m[8]*m[7]*m[13] + m[12]*m[5]*m[11] - m[12]*m[7]*m[9];
    inv[12] = -m[4]*m[9]*m[14]  + m[4]*m[10]*m[13] + m[8]*m[5]*m[14] - m[8]*m[6]*m[13] - m[12]*m[5]*m[10] + m[12]*m[6]*m[9];
    inv[1]  = -m[1]*m[10]*m[15] + m[1]*m[11]*m[14] + m[9]*m[2]*m[15] - m[9]*m[3]*m[14] - m[13]*m[2]*m[11] + m[13]*m[3]*m[10];
    inv[5]  =  m[0]*m[10]*m[15] - m[0]*m[11]*m[14] - m[8]*m[2]*m[15] + m[8]*m[3]*m[14] + m[12]*m[2]*m[11] - m[12]*m[3]*m[10];
    inv[9]  = -m[0]*m[9]*m[15]  + m[0]*m[11]*m[13] + m[8]*m[1]*m[15] - m[8]*m[3]*m[13] - m[12]*m[1]*m[11] + m[12]*m[3]*m[9];
    inv[13] =  m[0]*m[9]*m[14]  - m[0]*m[10]*m[13] - m[8]*m[1]*m[14] + m[8]*m[2]*m[13] + m[12]*m[1]*m[10] - m[12]*m[2]*m[9];
    inv[2]  =  m[1]*m[6]*m[15]  - m[1]*m[7]*m[14]  - m[5]*m[2]*m[15] + m[5]*m[3]*m[14] + m[13]*m[2]*m[7]  - m[13]*m[3]*m[6];
    inv[6]  = -m[0]*m[6]*m[15]  + m[0]*m[7]*m[14]  + m[4]*m[2]*m[15] - m[4]*m[3]*m[14] - m[12]*m[2]*m[7]  + m[12]*m[3]*m[6];
    inv[10] =  m[0]*m[5]*m[15]  - m[0]*m[7]*m[13]  - m[4]*m[1]*m[15] + m[4]*m[3]*m[13] + m[12]*m[1]*m[7]  - m[12]*m[3]*m[5];
    inv[14] = -m[0]*m[5]*m[14]  + m[0]*m[6]*m[13]  + m[4]*m[1]*m[14] - m[4]*m[2]*m[13] - m[12]*m[1]*m[6]  + m[12]*m[2]*m[5];
    inv[3]  = -m[1]*m[6]*m[11]  + m[1]*m[7]*m[10]  + m[5]*m[2]*m[11] - m[5]*m[3]*m[10] - m[9]*m[2]*m[7]   + m[9]*m[3]*m[6];
    inv[7]  =  m[0]*m[6]*m[11]  - m[0]*m[7]*m[10]  - m[4]*m[2]*m[11] + m[4]*m[3]*m[10] + m[8]*m[2]*m[7]   - m[8]*m[3]*m[6];
    inv[11] = -m[0]*m[5]*m[11]  + m[0]*m[7]*m[9]   + m[4]*m[1]*m[11] - m[4]*m[3]*m[9]  - m[8]*m[1]*m[7]   + m[8]*m[3]*m[5];
    inv[15] =  m[0]*m[5]*m[10]  - m[0]*m[6]*m[9]   - m[4]*m[1]*m[10] + m[4]*m[2]*m[9]  + m[8]*m[1]*m[6]   - m[8]*m[2]*m[5];
    float det = m[0]*inv[0] + m[1]*inv[4] + m[2]*inv[8] + m[3]*inv[12];
    float rd = 1.0f/det;
    for (int k = 0; k < 16; ++k) inv[k] *= rd;
}

// Per-batch params: P[b*24 + 0..8]=A1, [9..17]=A2, [18..20]=p0
__global__ void setup_k(const float* __restrict__ rt_inv, const float* __restrict__ k_inv,
                        const float* __restrict__ sdd,    const float* __restrict__ iso,
                        const float* __restrict__ affine, const float* __restrict__ rot,
                        const float* __restrict__ xyz,    float* __restrict__ P, int B)
{
    int b = blockIdx.x * blockDim.x + threadIdx.x;
    if (b >= B) return;

    const float* Mi = rt_inv + (size_t)b * 16;
    float rt[16];
    inv4x4(Mi, rt);

    float c[3];
    for (int r = 0; r < 3; ++r)
        c[r] = rt[r*4+0]*iso[0] + rt[r*4+1]*iso[1] + rt[r*4+2]*iso[2] + rt[r*4+3];

    float rx = rot[b*3+0], ry = rot[b*3+1], rz = rot[b*3+2];
    float th = sqrtf(rx*rx + ry*ry + rz*rz);
    float Rr[9];
    if (th < 1e-8f) {
        Rr[0]=1.f; Rr[1]=0.f; Rr[2]=0.f;
        Rr[3]=0.f; Rr[4]=1.f; Rr[5]=0.f;
        Rr[6]=0.f; Rr[7]=0.f; Rr[8]=1.f;
    } else {
        float kx = rx/th, ky = ry/th, kz = rz/th;
        float s = sinf(th), ct = cosf(th), v = 1.f - ct;
        Rr[0] = ct + v*kx*kx;     Rr[1] = v*kx*ky - s*kz;  Rr[2] = v*kx*kz + s*ky;
        Rr[3] = v*ky*kx + s*kz;   Rr[4] = ct + v*ky*ky;    Rr[5] = v*ky*kz - s*kx;
        Rr[6] = v*kz*kx - s*ky;   Rr[7] = v*kz*ky + s*kx;  Rr[8] = ct + v*kz*kz;
    }

    float tp[3];
    for (int r = 0; r < 3; ++r)
        tp[r] = c[r] + xyz[b*3+r] - (Rr[r*3+0]*c[0] + Rr[r*3+1]*c[1] + Rr[r*3+2]*c[2]);

    float G[9], t[3];
    for (int r = 0; r < 3; ++r) {
        for (int cc = 0; cc < 3; ++cc)
            G[r*3+cc] = Mi[r*4+0]*Rr[0*3+cc] + Mi[r*4+1]*Rr[1*3+cc] + Mi[r*4+2]*Rr[2*3+cc];
        t[r] = Mi[r*4+0]*tp[0] + Mi[r*4+1]*tp[1] + Mi[r*4+2]*tp[2] + Mi[r*4+3];
    }

    float Ai[16];
    inv4x4(affine, Ai);

    float p0[3];
    for (int r = 0; r < 3; ++r)
        p0[r] = Ai[r*4+0]*t[0] + Ai[r*4+1]*t[1] + Ai[r*4+2]*t[2] + Ai[r*4+3];

    float MG[9];
    for (int r = 0; r < 3; ++r)
        for (int cc = 0; cc < 3; ++cc)
            MG[r*3+cc] = Ai[r*4+0]*G[0*3+cc] + Ai[r*4+1]*G[1*3+cc] + Ai[r*4+2]*G[2*3+cc];

    const float* Ki = k_inv + (size_t)b * 9;
    float sd = sdd[b];
    float* Pb = P + (size_t)b * 24;
    for (int r = 0; r < 3; ++r)
        for (int cc = 0; cc < 3; ++cc) {
            Pb[r*3+cc]     = (MG[r*3+0]*Ki[0*3+cc] + MG[r*3+1]*Ki[1*3+cc] + MG[r*3+2]*Ki[2*3+cc]) * sd;
            Pb[9 + r*3+cc] = (G[r*3+0]*Ki[0*3+cc]  + G[r*3+1]*Ki[1*3+cc]  + G[r*3+2]*Ki[2*3+cc])  * sd;
        }
    Pb[18] = p0[0]; Pb[19] = p0[1]; Pb[20] = p0[2];
}

// 1 wave = 4 pixels (1x4 strip); lane = 16*p + t; lane t strides steps.
// Block (256 thr, 4 waves) owns a 4x4 pixel patch; 256 blocks = one 64x64
// supertile; supertiles chunked per XCD.
__global__ void __launch_bounds__(256, 6) drr8(
        const float* __restrict__ vol, const float* __restrict__ P,
        float* __restrict__ out,
        const int* __restrict__ Hp, const int* __restrict__ Wp, const int* __restrict__ Sp,
        int B, int D)
{
    const int H = *Hp, W = *Wp, S = *Sp;
    const int npix = H * W;
    const int nSj = (W + 63) >> 6, nSi = (H + 63) >> 6;
    const int nS = nSi * nSj;
    const int nStot = B * nS;
    const long long nVB = (long long)nStot << 8;   // 256 blocks per supertile

    const int tid  = threadIdx.x;
    const int wave = tid >> 6, lane = tid & 63;
    const int p    = lane >> 4, t = lane & 15;
    const int D1   = D - 1;
    const float Sf = (float)S, invS = 1.0f / Sf;

    for (long long vb = blockIdx.x; vb < nVB; vb += gridDim.x) {
        int st, within;
        if ((nStot & 7) == 0) {
            int xcd = (int)(vb & 7);
            long long slot = vb >> 3;
            st = xcd * (nStot >> 3) + (int)(slot >> 8);
            within = (int)(slot & 255);
        } else {
            st = (int)(vb >> 8);
            within = (int)(vb & 255);
        }
        int b = 0, stl = st;
        if (B > 1) { b = st / nS; stl = st - b * nS; }
        int si = stl / nSj, sj = stl - si * nSj;

        int r0 = (si << 6) + ((within >> 4) << 2) + wave;   // row
        int c0 = (sj << 6) + ((within & 15) << 2) + p;      // col
        bool valid = (r0 < H) && (c0 < W);
        int rr = min(r0, H - 1), cc = min(c0, W - 1);

        const float* Pb = P + 24 * __builtin_amdgcn_readfirstlane(b);
        float px = cc + 0.5f, py = rr + 0.5f;
        float ddx = fmaf(Pb[0], px, fmaf(Pb[1], py, Pb[2]));
        float ddy = fmaf(Pb[3], px, fmaf(Pb[4], py, Pb[5]));
        float ddz = fmaf(Pb[6], px, fmaf(Pb[7], py, Pb[8]));
        float rxx = fmaf(Pb[9], px, fmaf(Pb[10], py, Pb[11]));
        float ryy = fmaf(Pb[12], px, fmaf(Pb[13], py, Pb[14]));
        float rzz = fmaf(Pb[15], px, fmaf(Pb[16], py, Pb[17]));
        float p0x = Pb[18], p0y = Pb[19], p0z = Pb[20];

        float seglen = sqrtf(rxx*rxx + ryy*ryy + rzz*rzz) * invS;

        // slab clip to support box (-1, D), widened
        const float lo = -1.001f, hi = (float)D + 0.001f;
        float a0 = 0.f, a1 = 1.f;
        {
            float pp[3] = {p0x, p0y, p0z};
            float dd[3] = {ddx, ddy, ddz};
            #pragma unroll
            for (int ax = 0; ax < 3; ++ax) {
                if (fabsf(dd[ax]) > 1e-12f) {
                    float r  = 1.0f / dd[ax];
                    float t0 = (lo - pp[ax]) * r;
                    float t1 = (hi - pp[ax]) * r;
                    a0 = fmaxf(a0, fminf(t0, t1));
                    a1 = fminf(a1, fmaxf(t0, t1));
                } else if (pp[ax] < lo || pp[ax] > hi) {
                    a1 = -1.0f;
                }
            }
        }
        int slo = (int)ceilf(a0 * Sf - 0.5f) - 1;
        int shi = (int)floorf(a1 * Sf - 0.5f) + 1;
        if (slo < 0) slo = 0;
        if (shi > S - 1) shi = S - 1;

        float sum = 0.f;

        // ---- phase-split main block: 6 samples/thread ----
        {
            f2    q[24];
            float xs[6], ys[6], zs[6];

            #pragma unroll
            for (int it = 0; it < 6; ++it) {
                int s = slo + t + (it << 4);
                float al = (s + 0.5f) * invS;
                float x = fmaf(al, ddx, p0x);
                float y = fmaf(al, ddy, p0y);
                float z = fmaf(al, ddz, p0z);
                xs[it] = x; ys[it] = y; zs[it] = z;
                int ix = (int)floorf(x), iy = (int)floorf(y), iz = (int)floorf(z);
                int x0c = min(max(ix, 0), D1), x1c = min(max(ix + 1, 0), D1);
                int y0c = min(max(iy, 0), D1), y1c = min(max(iy + 1, 0), D1);
                int z0c = min(max(iz, 0), D - 2);
                int a0r = x0c * D, a1r = x1c * D;
                q[it*4+0] = *(const f2*)(vol + (unsigned)((a0r + y0c) * D + z0c));
                q[it*4+1] = *(const f2*)(vol + (unsigned)((a0r + y1c) * D + z0c));
                q[it*4+2] = *(const f2*)(vol + (unsigned)((a1r + y0c) * D + z0c));
                q[it*4+3] = *(const f2*)(vol + (unsigned)((a1r + y1c) * D + z0c));
            }

            #pragma unroll
            for (int it = 0; it < 6; ++it) {
                int s = slo + t + (it << 4);
                float act = (s <= shi) ? 1.0f : 0.0f;
                float x = xs[it], y = ys[it], z = zs[it];
                float fx = floorf(x), fy = floorf(y), fz = floorf(z);
                int ix = (int)fx, iy = (int)fy, iz = (int)fz;
                float tx = x - fx, ty = y - fy, tz = z - fz;
                int z0c = min(max(iz, 0), D - 2);
                bool e0 = (iz == z0c), em = (iz == z0c - 1), ep = (iz == z0c + 1);
                f2 q00 = q[it*4+0], q01 = q[it*4+1], q10 = q[it*4+2], q11 = q[it*4+3];
                float v0, v1, c00, c01, c10, c11;
                v0 = e0 ? q00.x : (ep ? q00.y : 0.f);
                v1 = e0 ? q00.y : (em ? q00.x : 0.f);
                c00 = fmaf(tz, v1 - v0, v0);
                v0 = e0 ? q01.x : (ep ? q01.y : 0.f);
                v1 = e0 ? q01.y : (em ? q01.x : 0.f);
                c01 = fmaf(tz, v1 - v0, v0);
                v0 = e0 ? q10.x : (ep ? q10.y : 0.f);
                v1 = e0 ? q10.y : (em ? q10.x : 0.f);
                c10 = fmaf(tz, v1 - v0, v0);
                v0 = e0 ? q11.x : (ep ? q11.y : 0.f);
                v1 = e0 ? q11.y : (em ? q11.x : 0.f);
                c11 = fmaf(tz, v1 - v0, v0);
                float wy0 = ((unsigned)iy       < (unsigned)D) ? 1.f - ty : 0.f;
                float wy1 = ((unsigned)(iy + 1) < (unsigned)D) ? ty       : 0.f;
                float wx0 = ((unsigned)ix       < (unsigned)D) ? 1.f - tx : 0.f;
                float wx1 = ((unsigned)(ix + 1) < (unsigned)D) ? tx       : 0.f;
                float s0 = fmaf(wy0, c00, wy1 * c01);
                float s1 = fmaf(wy0, c10, wy1 * c11);
                sum = fmaf(act * wx0, s0, sum);
                sum = fmaf(act * wx1, s1, sum);
            }
        }

        // generic tail (never taken for paths <= 96 steps)
        for (int s = slo + 96 + t; s <= shi; s += 16) {
            float al = (s + 0.5f) * invS;
            float x = fmaf(al, ddx, p0x);
            float y = fmaf(al, ddy, p0y);
            float z = fmaf(al, ddz, p0z);
            float fx = floorf(x), fy = floorf(y), fz = floorf(z);
            int ix = (int)fx, iy = (int)fy, iz = (int)fz;
            float tx = x - fx, ty = y - fy, tz = z - fz;
            int x0c = min(max(ix, 0), D1), x1c = min(max(ix + 1, 0), D1);
            int y0c = min(max(iy, 0), D1), y1c = min(max(iy + 1, 0), D1);
            int z0c = min(max(iz, 0), D - 2);
            int a0r = x0c * D, a1r = x1c * D;
            f2 q00 = *(const f2*)(vol + (unsigned)((a0r + y0c) * D + z0c));
            f2 q01 = *(const f2*)(vol + (unsigned)((a0r + y1c) * D + z0c));
            f2 q10 = *(const f2*)(vol + (unsigned)((a1r + y0c) * D + z0c));
            f2 q11 = *(const f2*)(vol + (unsigned)((a1r + y1c) * D + z0c));
            bool e0 = (iz == z0c), em = (iz == z0c - 1), ep = (iz == z0c + 1);
            float v0, v1, c00, c01, c10, c11;
            v0 = e0 ? q00.x : (ep ? q00.y : 0.f);
            v1 = e0 ? q00.y : (em ? q00.x : 0.f);
            c00 = fmaf(tz, v1 - v0, v0);
            v0 = e0 ? q01.x : (ep ? q01.y : 0.f);
            v1 = e0 ? q01.y : (em ? q01.x : 0.f);
            c01 = fmaf(tz, v1 - v0, v0);
            v0 = e0 ? q10.x : (ep ? q10.y : 0.f);
            v1 = e0 ? q10.y : (em ? q10.x : 0.f);
            c10 = fmaf(tz, v1 - v0, v0);
            v0 = e0 ? q11.x : (ep ? q11.y : 0.f);
            v1 = e0 ? q11.y : (em ? q11.x : 0.f);
            c11 = fmaf(tz, v1 - v0, v0);
            float wy0 = ((unsigned)iy       < (unsigned)D) ? 1.f - ty : 0.f;
            float wy1 = ((unsigned)(iy + 1) < (unsigned)D) ? ty       : 0.f;
            float wx0 = ((unsigned)ix       < (unsigned)D) ? 1.f - tx : 0.f;
            float wx1 = ((unsigned)(ix + 1) < (unsigned)D) ? tx       : 0.f;
            float s0 = fmaf(wy0, c00, wy1 * c01);
            float s1 = fmaf(wy0, c10, wy1 * c11);
            sum = fmaf(wx0, s0, sum);
            sum = fmaf(wx1, s1, sum);
        }

        sum += __shfl_xor(sum, 8, 16);
        sum += __shfl_xor(sum, 4, 16);
        sum += __shfl_xor(sum, 2, 16);
        sum += __shfl_xor(sum, 1, 16);

        if (t == 0 && valid)
            out[(size_t)b * npix + (size_t)rr * W + cc] = sum * seglen;
    }
}

extern "C" void kernel_launch(void* const* d_in, const int* in_sizes, int n_in,
                              void* d_out, int out_size, void* d_ws, size_t ws_size,
                              hipStream_t stream)
{
    const float* volume = (const float*)d_in[0];
    const float* rt_inv = (const float*)d_in[1];
    const float* k_inv  = (const float*)d_in[2];
    const float* sdd    = (const float*)d_in[3];
    const float* iso    = (const float*)d_in[4];
    const float* affine = (const float*)d_in[5];
    const float* rot    = (const float*)d_in[6];
    const float* xyz    = (const float*)d_in[7];
    const int*   Hp     = (const int*)d_in[8];
    const int*   Wp     = (const int*)d_in[9];
    const int*   Sp     = (const int*)d_in[10];

    int B = in_sizes[1] / 16;                         // rt_inv is (B,4,4)
    int D = (int)lroundf(cbrtf((float)in_sizes[0]));  // volume is (D,D,D)

    float* P = (float*)d_ws;
    setup_k<<<(B + 63) / 64, 64, 0, stream>>>(rt_inv, k_inv, sdd, iso, affine, rot, xyz, P, B);

    // one block per 4x4-pixel patch via device-side supertile walk
    long long hw = (long long)out_size / B;
    long long vbl = (long long)B * ((hw + 4095) >> 12) * 256;
    if (vbl > (1 << 22)) vbl = (1 << 22);
    drr8<<<(int)vbl, 256, 0, stream>>>(volume, P, (float*)d_out, Hp, Wp, Sp, B, D);
    (void)n_in; (void)ws_size;
}